// Round 1
// baseline (1445.975 us; speedup 1.0000x reference)
//
#include <hip/hip_runtime.h>

#define KHOPS 8

// ---------------------------------------------------------------------------
// init: T = 0, bp = 0.5   (ws is poisoned 0xAA before every timed launch)
// ---------------------------------------------------------------------------
__global__ void init_kernel(float* __restrict__ T, float* __restrict__ bp, int n_links) {
    int i = blockIdx.x * blockDim.x + threadIdx.x;
    if (i < n_links) {
        T[i]  = 0.0f;
        bp[i] = 0.5f;
    }
}

// ---------------------------------------------------------------------------
// scatter: one thread per path. traffic chain over 8 hops, atomic T[link] +=
// traffic BEFORE attenuation (matches reference scan ordering: segment_sum
// uses pre-multiply traffic at each hop).
// ---------------------------------------------------------------------------
__global__ void scatter_kernel(const float* __restrict__ P,
                               const int*   __restrict__ pl_edges,
                               const float* __restrict__ bp,
                               float*       __restrict__ T,
                               int n_paths) {
    int p = blockIdx.x * blockDim.x + threadIdx.x;
    if (p >= n_paths) return;

    int e[KHOPS];
#pragma unroll
    for (int k = 0; k < KHOPS; ++k)
        e[k] = pl_edges[k * n_paths + p] - n_paths;   // coalesced per hop

    float b[KHOPS];
#pragma unroll
    for (int k = 0; k < KHOPS; ++k)
        b[k] = bp[e[k]];                              // 8 independent L2 gathers

    float t = P[3 * p + 1];                           // A[p] = P[p][1]
#pragma unroll
    for (int k = 0; k < KHOPS; ++k) {
        unsafeAtomicAdd(&T[e[k]], t);                 // HW global_atomic_add_f32
        t *= (1.0f - b[k]);
    }
}

// ---------------------------------------------------------------------------
// link update: rho = T/cap; bp = (1-rho) rho^32 / (1 - rho^33 + 1e-8);
// also re-zeros T for the next iteration.
// ---------------------------------------------------------------------------
__global__ void link_update_kernel(const float* __restrict__ L,
                                   float*       __restrict__ T,
                                   float*       __restrict__ bp,
                                   float*       __restrict__ rho_out,
                                   int n_links) {
    int l = blockIdx.x * blockDim.x + threadIdx.x;
    if (l >= n_links) return;
    float cap = L[l] * (1.0f / 1000.0f);
    float rho = T[l] / cap;
    rho_out[l] = rho;
    float r2 = rho * rho, r4 = r2 * r2, r8 = r4 * r4, r16 = r8 * r8;
    float r32 = r16 * r16;
    float r33 = r32 * rho;
    bp[l] = (1.0f - rho) * r32 / (1.0f - r33 + 1e-8f);
    T[l] = 0.0f;
}

// ---------------------------------------------------------------------------
// epilogue (per link): pi0, Lq, pi0_final, X_l; writes the (n_links,3) stacked
// output [Lq, rho, pi0_final] and stashes X_l for the path gather.
// ---------------------------------------------------------------------------
__global__ void epilogue_kernel(const float* __restrict__ L,
                                const float* __restrict__ rho_in,
                                float*       __restrict__ Xl,
                                float*       __restrict__ out_links,  // d_out + n_paths
                                int n_links) {
    int l = blockIdx.x * blockDim.x + threadIdx.x;
    if (l >= n_links) return;
    float rho = rho_in[l];
    float r2 = rho * rho, r4 = r2 * r2, r8 = r4 * r4, r16 = r8 * r8;
    float r32 = r16 * r16;
    float r33 = r32 * rho;
    float pi0 = (1.0f - rho) / (1.0f - r33);          // reference has no epsilon here

    // S = sum_{m=0..32} coeff(m) * rho^m, coeff(0)=1, coeff(m)=m
    float S = 1.0f, rp = 1.0f;
#pragma unroll
    for (int m = 1; m <= 32; ++m) { rp *= rho; S += (float)m * rp; }

    float Lq   = pi0 * S * (1.0f / 32.0f);
    float pi0f = pi0 * r32;
    float X    = Lq * 32000.0f / L[l];

    Xl[l] = X;
    out_links[3 * l + 0] = Lq;
    out_links[3 * l + 1] = rho;
    out_links[3 * l + 2] = pi0f;
}

// ---------------------------------------------------------------------------
// gather: res[p] = sum_k X_l[e[k][p]]  (pl_paths is the identity, so the final
// segment_sum is a per-path private sum — no atomics)
// ---------------------------------------------------------------------------
__global__ void gather_kernel(const int*   __restrict__ pl_edges,
                              const float* __restrict__ Xl,
                              float*       __restrict__ res,
                              int n_paths) {
    int p = blockIdx.x * blockDim.x + threadIdx.x;
    if (p >= n_paths) return;
    float s = 0.0f;
#pragma unroll
    for (int k = 0; k < KHOPS; ++k) {
        int e = pl_edges[k * n_paths + p] - n_paths;
        s += Xl[e];
    }
    res[p] = s;
}

// ---------------------------------------------------------------------------
extern "C" void kernel_launch(void* const* d_in, const int* in_sizes, int n_in,
                              void* d_out, int out_size, void* d_ws, size_t ws_size,
                              hipStream_t stream) {
    const float* P        = (const float*)d_in[0];   // (n_paths, 3)
    const float* L        = (const float*)d_in[1];   // (n_links, 1)
    // d_in[2] = pl_paths — identity per hop, unused
    const int*   pl_edges = (const int*)d_in[3];     // (KHOPS, n_paths)

    const int n_paths = in_sizes[0] / 3;
    const int n_links = in_sizes[1];
    const int num_iterations = 3;                    // fixed by setup_inputs

    // workspace layout (4 * n_links floats = 800 KB)
    float* T   = (float*)d_ws;
    float* bp  = T   + n_links;
    float* rho = bp  + n_links;
    float* Xl  = rho + n_links;

    float* res       = (float*)d_out;                // (n_paths,)
    float* out_links = res + n_paths;                // (n_links, 3) row-major

    const int bs = 256;
    const int gl = (n_links + bs - 1) / bs;
    const int gp = (n_paths + bs - 1) / bs;

    init_kernel<<<gl, bs, 0, stream>>>(T, bp, n_links);
    for (int it = 0; it < num_iterations; ++it) {
        scatter_kernel<<<gp, bs, 0, stream>>>(P, pl_edges, bp, T, n_paths);
        link_update_kernel<<<gl, bs, 0, stream>>>(L, T, bp, rho, n_links);
    }
    epilogue_kernel<<<gl, bs, 0, stream>>>(L, rho, Xl, out_links, n_links);
    gather_kernel<<<gp, bs, 0, stream>>>(pl_edges, Xl, res, n_paths);
}

// Round 2
// 1313.396 us; speedup vs baseline: 1.1009x; 1.1009x over previous
//
#include <hip/hip_runtime.h>

#define KHOPS 8
#define MAXREP 16

// ---------------------------------------------------------------------------
// init: zero all R replicas of T, bp = 0.5
// ---------------------------------------------------------------------------
__global__ void init_kernel(float* __restrict__ Trep, float* __restrict__ bp,
                            int n_links, int R) {
    int i = blockIdx.x * blockDim.x + threadIdx.x;
    if (i < n_links * R) {
        Trep[i] = 0.0f;
        if (i < n_links) bp[i] = 0.5f;
    }
}

// ---------------------------------------------------------------------------
// scatter: one thread per path, 8-hop traffic chain, atomics into the
// blockIdx-selected replica of T (replica-major: T[r][link]) to cut
// same-cache-line serialization by R.
// ---------------------------------------------------------------------------
__global__ void scatter_kernel(const float* __restrict__ P,
                               const int*   __restrict__ pl_edges,
                               const float* __restrict__ bp,
                               float*       __restrict__ Trep,
                               int n_paths, int n_links, int rmask) {
    int p = blockIdx.x * blockDim.x + threadIdx.x;
    if (p >= n_paths) return;

    float* Tmine = Trep + (size_t)(blockIdx.x & rmask) * n_links;

    int e[KHOPS];
#pragma unroll
    for (int k = 0; k < KHOPS; ++k)
        e[k] = pl_edges[k * n_paths + p] - n_paths;   // coalesced per hop

    float b[KHOPS];
#pragma unroll
    for (int k = 0; k < KHOPS; ++k)
        b[k] = bp[e[k]];                              // random 4B gathers (L2/L3)

    float t = P[3 * p + 1];                           // A[p] = P[p][1]
#pragma unroll
    for (int k = 0; k < KHOPS; ++k) {
        unsafeAtomicAdd(&Tmine[e[k]], t);             // HW global_atomic_add_f32
        t *= (1.0f - b[k]);
    }
}

// ---------------------------------------------------------------------------
// link update: T = sum of replicas (and re-zero them); rho = T/cap;
// bp = (1-rho) rho^32 / (1 - rho^33 + 1e-8)
// ---------------------------------------------------------------------------
__global__ void link_update_kernel(const float* __restrict__ L,
                                   float*       __restrict__ Trep,
                                   float*       __restrict__ bp,
                                   float*       __restrict__ rho_out,
                                   int n_links, int R) {
    int l = blockIdx.x * blockDim.x + threadIdx.x;
    if (l >= n_links) return;
    float T = 0.0f;
    for (int r = 0; r < R; ++r) {
        size_t idx = (size_t)r * n_links + l;
        T += Trep[idx];
        Trep[idx] = 0.0f;                             // ready for next iteration
    }
    float cap = L[l] * (1.0f / 1000.0f);
    float rho = T / cap;
    rho_out[l] = rho;
    float r2 = rho * rho, r4 = r2 * r2, r8 = r4 * r4, r16 = r8 * r8;
    float r32 = r16 * r16;
    float r33 = r32 * rho;
    bp[l] = (1.0f - rho) * r32 / (1.0f - r33 + 1e-8f);
}

// ---------------------------------------------------------------------------
// epilogue (per link): pi0, Lq, pi0_final, X_l; writes (n_links,3) stacked
// [Lq, rho, pi0_final] and stashes X_l for the path gather.
// ---------------------------------------------------------------------------
__global__ void epilogue_kernel(const float* __restrict__ L,
                                const float* __restrict__ rho_in,
                                float*       __restrict__ Xl,
                                float*       __restrict__ out_links,  // d_out + n_paths
                                int n_links) {
    int l = blockIdx.x * blockDim.x + threadIdx.x;
    if (l >= n_links) return;
    float rho = rho_in[l];
    float r2 = rho * rho, r4 = r2 * r2, r8 = r4 * r4, r16 = r8 * r8;
    float r32 = r16 * r16;
    float r33 = r32 * rho;
    float pi0 = (1.0f - rho) / (1.0f - r33);          // reference: no epsilon here

    float S = 1.0f, rp = 1.0f;
#pragma unroll
    for (int m = 1; m <= 32; ++m) { rp *= rho; S += (float)m * rp; }

    float Lq   = pi0 * S * (1.0f / 32.0f);
    float pi0f = pi0 * r32;
    float X    = Lq * 32000.0f / L[l];

    Xl[l] = X;
    out_links[3 * l + 0] = Lq;
    out_links[3 * l + 1] = rho;
    out_links[3 * l + 2] = pi0f;
}

// ---------------------------------------------------------------------------
// gather: res[p] = sum_k X_l[e[k][p]]   (pl_paths is identity → no atomics)
// ---------------------------------------------------------------------------
__global__ void gather_kernel(const int*   __restrict__ pl_edges,
                              const float* __restrict__ Xl,
                              float*       __restrict__ res,
                              int n_paths) {
    int p = blockIdx.x * blockDim.x + threadIdx.x;
    if (p >= n_paths) return;
    float s = 0.0f;
#pragma unroll
    for (int k = 0; k < KHOPS; ++k) {
        int e = pl_edges[k * n_paths + p] - n_paths;
        s += Xl[e];
    }
    res[p] = s;
}

// ---------------------------------------------------------------------------
extern "C" void kernel_launch(void* const* d_in, const int* in_sizes, int n_in,
                              void* d_out, int out_size, void* d_ws, size_t ws_size,
                              hipStream_t stream) {
    const float* P        = (const float*)d_in[0];   // (n_paths, 3)
    const float* L        = (const float*)d_in[1];   // (n_links, 1)
    // d_in[2] = pl_paths — identity per hop, unused
    const int*   pl_edges = (const int*)d_in[3];     // (KHOPS, n_paths)

    const int n_paths = in_sizes[0] / 3;
    const int n_links = in_sizes[1];
    const int num_iterations = 3;

    // Pick replica count R (power of 2, <=16) that fits the workspace:
    // need (R + 3) * n_links floats.
    int R = 1;
    while (R < MAXREP &&
           (size_t)(2 * R + 3) * (size_t)n_links * sizeof(float) <= ws_size)
        R *= 2;
    const int rmask = R - 1;

    // workspace layout
    float* Trep = (float*)d_ws;                      // R * n_links
    float* bp   = Trep + (size_t)R * n_links;
    float* rho  = bp + n_links;
    float* Xl   = rho + n_links;

    float* res       = (float*)d_out;                // (n_paths,)
    float* out_links = res + n_paths;                // (n_links, 3) row-major

    const int bs = 256;
    const int gl  = (n_links + bs - 1) / bs;
    const int glR = (n_links * R + bs - 1) / bs;
    const int gp  = (n_paths + bs - 1) / bs;

    init_kernel<<<glR, bs, 0, stream>>>(Trep, bp, n_links, R);
    for (int it = 0; it < num_iterations; ++it) {
        scatter_kernel<<<gp, bs, 0, stream>>>(P, pl_edges, bp, Trep,
                                              n_paths, n_links, rmask);
        link_update_kernel<<<gl, bs, 0, stream>>>(L, Trep, bp, rho, n_links, R);
    }
    epilogue_kernel<<<gl, bs, 0, stream>>>(L, rho, Xl, out_links, n_links);
    gather_kernel<<<gp, bs, 0, stream>>>(pl_edges, Xl, res, n_paths);
}

// Round 3
// 852.478 us; speedup vs baseline: 1.6962x; 1.5407x over previous
//
#include <hip/hip_runtime.h>

#define KHOPS 8
#define CHUNK 16384          // links per LDS chunk (64 KB of fp32)
#define BS    1024           // scatter block size
#define MAXGRID 512
#define MINGRID 4

// ---------------------------------------------------------------------------
// init: A[p] = P[p][1] (compact traffic source), bp = 0.5
// ---------------------------------------------------------------------------
__global__ void init_kernel(const float* __restrict__ P,
                            float* __restrict__ A,
                            float* __restrict__ bp,
                            int n_paths, int n_links) {
    int i = blockIdx.x * blockDim.x + threadIdx.x;
    if (i < n_paths) A[i] = P[3 * i + 1];
    if (i < n_links) bp[i] = 0.5f;
}

// ---------------------------------------------------------------------------
// scatter: LDS pre-aggregation. C link-chunks of 16K; per chunk each block
// re-walks its paths (traffic chain recompute is 8 fma + 8 L2 gathers) and
// LDS-atomic-adds in-chunk hops, then flushes the chunk to its PRIVATE
// replica slice Trep[block][*] with plain coalesced stores. No global atomics.
// ---------------------------------------------------------------------------
__global__ __launch_bounds__(BS) void scatter_kernel(
        const float* __restrict__ A,
        const int*   __restrict__ pl_edges,
        const float* __restrict__ bp,
        float*       __restrict__ Trep,       // [gridDim.x][n_links]
        int n_paths, int n_links) {
    __shared__ float h[CHUNK];
    const int tid = threadIdx.x;
    const int nthreads = gridDim.x * BS;
    float* Tmine = Trep + (size_t)blockIdx.x * n_links;

    const int nchunks = (n_links + CHUNK - 1) / CHUNK;
    for (int c = 0; c < nchunks; ++c) {
        const int base = c * CHUNK;

        for (int i = tid; i < CHUNK; i += BS) h[i] = 0.0f;
        __syncthreads();

        for (int p = blockIdx.x * BS + tid; p < n_paths; p += nthreads) {
            int e[KHOPS];
            float b[KHOPS];
#pragma unroll
            for (int k = 0; k < KHOPS; ++k)
                e[k] = pl_edges[k * n_paths + p] - n_paths;  // coalesced per hop
#pragma unroll
            for (int k = 0; k < KHOPS; ++k)
                b[k] = bp[e[k]];                             // L2-resident gathers
            float t = A[p];
#pragma unroll
            for (int k = 0; k < KHOPS; ++k) {
                unsigned el = (unsigned)(e[k] - base);
                if (el < CHUNK) unsafeAtomicAdd(&h[el], t);  // ds_add_f32
                t *= (1.0f - b[k]);
            }
        }
        __syncthreads();

        for (int i = tid; i < CHUNK; i += BS) {
            int l = base + i;
            if (l < n_links) Tmine[l] = h[i];                // non-atomic flush
        }
        __syncthreads();
    }
}

// ---------------------------------------------------------------------------
// link update: T = sum over R replicas; rho = T/cap;
// bp = (1-rho) rho^32 / (1 - rho^33 + 1e-8)
// ---------------------------------------------------------------------------
__global__ void link_update_kernel(const float* __restrict__ L,
                                   const float* __restrict__ Trep,
                                   float*       __restrict__ bp,
                                   float*       __restrict__ rho_out,
                                   int n_links, int R) {
    int l = blockIdx.x * blockDim.x + threadIdx.x;
    if (l >= n_links) return;
    float T = 0.0f;
    for (int r = 0; r < R; ++r)
        T += Trep[(size_t)r * n_links + l];                  // coalesced per r
    float cap = L[l] * (1.0f / 1000.0f);
    float rho = T / cap;
    rho_out[l] = rho;
    float r2 = rho * rho, r4 = r2 * r2, r8 = r4 * r4, r16 = r8 * r8;
    float r32 = r16 * r16;
    float r33 = r32 * rho;
    bp[l] = (1.0f - rho) * r32 / (1.0f - r33 + 1e-8f);
}

// ---------------------------------------------------------------------------
// epilogue (per link): writes (n_links,3) stacked [Lq, rho, pi0_final],
// stashes X_l for the path gather.
// ---------------------------------------------------------------------------
__global__ void epilogue_kernel(const float* __restrict__ L,
                                const float* __restrict__ rho_in,
                                float*       __restrict__ Xl,
                                float*       __restrict__ out_links,
                                int n_links) {
    int l = blockIdx.x * blockDim.x + threadIdx.x;
    if (l >= n_links) return;
    float rho = rho_in[l];
    float r2 = rho * rho, r4 = r2 * r2, r8 = r4 * r4, r16 = r8 * r8;
    float r32 = r16 * r16;
    float r33 = r32 * rho;
    float pi0 = (1.0f - rho) / (1.0f - r33);                 // no epsilon (ref)

    float S = 1.0f, rp = 1.0f;
#pragma unroll
    for (int m = 1; m <= 32; ++m) { rp *= rho; S += (float)m * rp; }

    float Lq   = pi0 * S * (1.0f / 32.0f);
    float pi0f = pi0 * r32;
    float X    = Lq * 32000.0f / L[l];

    Xl[l] = X;
    out_links[3 * l + 0] = Lq;
    out_links[3 * l + 1] = rho;
    out_links[3 * l + 2] = pi0f;
}

// ---------------------------------------------------------------------------
// gather: res[p] = sum_k X_l[e[k][p]]   (pl_paths is identity → no atomics)
// ---------------------------------------------------------------------------
__global__ void gather_kernel(const int*   __restrict__ pl_edges,
                              const float* __restrict__ Xl,
                              float*       __restrict__ res,
                              int n_paths) {
    int p = blockIdx.x * blockDim.x + threadIdx.x;
    if (p >= n_paths) return;
    float s = 0.0f;
#pragma unroll
    for (int k = 0; k < KHOPS; ++k) {
        int e = pl_edges[k * n_paths + p] - n_paths;
        s += Xl[e];
    }
    res[p] = s;
}

// ---------------------------------------------------------------------------
extern "C" void kernel_launch(void* const* d_in, const int* in_sizes, int n_in,
                              void* d_out, int out_size, void* d_ws, size_t ws_size,
                              hipStream_t stream) {
    const float* P        = (const float*)d_in[0];   // (n_paths, 3)
    const float* L        = (const float*)d_in[1];   // (n_links, 1)
    const int*   pl_edges = (const int*)d_in[3];     // (KHOPS, n_paths)

    const int n_paths = in_sizes[0] / 3;
    const int n_links = in_sizes[1];
    const int num_iterations = 3;

    // workspace: A (n_paths) | bp | rho | Xl (3*n_links) | Trep (R*n_links)
    size_t floats_avail = ws_size / sizeof(float);
    long   spare = (long)floats_avail - (long)n_paths - 3L * n_links;
    int R = (int)(spare / n_links);
    if (R > MAXGRID) R = MAXGRID;
    if (R < MINGRID) R = MINGRID;   // assume ws is at least ~5 MB

    float* A    = (float*)d_ws;
    float* bp   = A   + n_paths;
    float* rho  = bp  + n_links;
    float* Xl   = rho + n_links;
    float* Trep = Xl  + n_links;

    float* res       = (float*)d_out;                // (n_paths,)
    float* out_links = res + n_paths;                // (n_links, 3)

    const int bs = 256;
    const int gl = (n_links + bs - 1) / bs;
    const int gp = (n_paths + bs - 1) / bs;
    const int gi = (n_paths > n_links ? n_paths : n_links + bs - 1) / bs + 1;

    init_kernel<<<gi, bs, 0, stream>>>(P, A, bp, n_paths, n_links);
    for (int it = 0; it < num_iterations; ++it) {
        scatter_kernel<<<R, BS, 0, stream>>>(A, pl_edges, bp, Trep,
                                             n_paths, n_links);
        link_update_kernel<<<gl, bs, 0, stream>>>(L, Trep, bp, rho, n_links, R);
    }
    epilogue_kernel<<<gl, bs, 0, stream>>>(L, rho, Xl, out_links, n_links);
    gather_kernel<<<gp, bs, 0, stream>>>(pl_edges, Xl, res, n_paths);
}

// Round 4
// 367.105 us; speedup vs baseline: 3.9389x; 2.3222x over previous
//
#include <hip/hip_runtime.h>

#define KHOPS 8
#define CHUNK 25088          // links per LDS chunk: 100352 B (gfx950 has 160 KB/CU)
#define BS    1024           // scatter block size
#define MAXGRID 256
#define MINGRID 64
#define P1    8              // replica-merge fan-in stage-1 output count

// ---------------------------------------------------------------------------
// init: A[p] = P[p][1] (compact traffic source), bp = 0.5
// ---------------------------------------------------------------------------
__global__ void init_kernel(const float* __restrict__ P,
                            float* __restrict__ A,
                            float* __restrict__ bp,
                            int n_paths, int n_links) {
    int i = blockIdx.x * blockDim.x + threadIdx.x;
    if (i < n_paths) A[i] = P[3 * i + 1];
    if (i < n_links) bp[i] = 0.5f;
}

// ---------------------------------------------------------------------------
// scatter: LDS pre-aggregation, 2 chunks of 25088 links (100 KB LDS).
// Each block re-walks its grid-stride path share per chunk (8 coalesced edge
// loads + 8 L2 gathers + chain fma), LDS-atomic-adds in-chunk hops, then
// flushes the chunk to its PRIVATE replica slice with plain coalesced stores.
// ---------------------------------------------------------------------------
__global__ __launch_bounds__(BS) void scatter_kernel(
        const float* __restrict__ A,
        const int*   __restrict__ pl_edges,
        const float* __restrict__ bp,
        float*       __restrict__ Trep,       // [gridDim.x][n_links]
        int n_paths, int n_links) {
    __shared__ float h[CHUNK];
    const int tid = threadIdx.x;
    const int nthreads = gridDim.x * BS;
    float* Tmine = Trep + (size_t)blockIdx.x * n_links;

    const int nchunks = (n_links + CHUNK - 1) / CHUNK;
    for (int c = 0; c < nchunks; ++c) {
        const int base = c * CHUNK;

        for (int i = tid; i < CHUNK; i += BS) h[i] = 0.0f;
        __syncthreads();

        for (int p = blockIdx.x * BS + tid; p < n_paths; p += nthreads) {
            int e[KHOPS];
            float b[KHOPS];
#pragma unroll
            for (int k = 0; k < KHOPS; ++k)
                e[k] = pl_edges[k * n_paths + p] - n_paths;  // coalesced per hop
#pragma unroll
            for (int k = 0; k < KHOPS; ++k)
                b[k] = bp[e[k]];                             // L2-resident gathers
            float t = A[p];
#pragma unroll
            for (int k = 0; k < KHOPS; ++k) {
                unsigned el = (unsigned)(e[k] - base);
                if (el < CHUNK) unsafeAtomicAdd(&h[el], t);  // ds_add_f32
                t *= (1.0f - b[k]);
            }
        }
        __syncthreads();

        for (int i = tid; i < CHUNK; i += BS) {
            int l = base + i;
            if (l < n_links) Tmine[l] = h[i];                // non-atomic flush
        }
        __syncthreads();
    }
}

// ---------------------------------------------------------------------------
// merge stage 1: partial[q][l] = sum_{r == q (mod P1)} Trep[r][l]
// grid: (ceil(n_links/bs), P1). Coalesced in l; loads independent/unrolled.
// ---------------------------------------------------------------------------
__global__ void merge_kernel(const float* __restrict__ Trep,
                             float*       __restrict__ partial,
                             int n_links, int R) {
    int l = blockIdx.x * blockDim.x + threadIdx.x;
    int q = blockIdx.y;
    if (l >= n_links) return;
    float s = 0.0f;
    for (int r = q; r < R; r += P1)
        s += Trep[(size_t)r * n_links + l];
    partial[(size_t)q * n_links + l] = s;
}

// ---------------------------------------------------------------------------
// link update: T = sum of P1 partials; rho = T/cap;
// bp = (1-rho) rho^32 / (1 - rho^33 + 1e-8)
// ---------------------------------------------------------------------------
__global__ void link_update_kernel(const float* __restrict__ L,
                                   const float* __restrict__ partial,
                                   float*       __restrict__ bp,
                                   float*       __restrict__ rho_out,
                                   int n_links) {
    int l = blockIdx.x * blockDim.x + threadIdx.x;
    if (l >= n_links) return;
    float T = 0.0f;
#pragma unroll
    for (int q = 0; q < P1; ++q)
        T += partial[(size_t)q * n_links + l];
    float cap = L[l] * (1.0f / 1000.0f);
    float rho = T / cap;
    rho_out[l] = rho;
    float r2 = rho * rho, r4 = r2 * r2, r8 = r4 * r4, r16 = r8 * r8;
    float r32 = r16 * r16;
    float r33 = r32 * rho;
    bp[l] = (1.0f - rho) * r32 / (1.0f - r33 + 1e-8f);
}

// ---------------------------------------------------------------------------
// epilogue (per link): writes (n_links,3) stacked [Lq, rho, pi0_final],
// stashes X_l for the path gather.
// ---------------------------------------------------------------------------
__global__ void epilogue_kernel(const float* __restrict__ L,
                                const float* __restrict__ rho_in,
                                float*       __restrict__ Xl,
                                float*       __restrict__ out_links,
                                int n_links) {
    int l = blockIdx.x * blockDim.x + threadIdx.x;
    if (l >= n_links) return;
    float rho = rho_in[l];
    float r2 = rho * rho, r4 = r2 * r2, r8 = r4 * r4, r16 = r8 * r8;
    float r32 = r16 * r16;
    float r33 = r32 * rho;
    float pi0 = (1.0f - rho) / (1.0f - r33);                 // no epsilon (ref)

    float S = 1.0f, rp = 1.0f;
#pragma unroll
    for (int m = 1; m <= 32; ++m) { rp *= rho; S += (float)m * rp; }

    float Lq   = pi0 * S * (1.0f / 32.0f);
    float pi0f = pi0 * r32;
    float X    = Lq * 32000.0f / L[l];

    Xl[l] = X;
    out_links[3 * l + 0] = Lq;
    out_links[3 * l + 1] = rho;
    out_links[3 * l + 2] = pi0f;
}

// ---------------------------------------------------------------------------
// gather: res[p] = sum_k X_l[e[k][p]]   (pl_paths is identity → no atomics)
// ---------------------------------------------------------------------------
__global__ void gather_kernel(const int*   __restrict__ pl_edges,
                              const float* __restrict__ Xl,
                              float*       __restrict__ res,
                              int n_paths) {
    int p = blockIdx.x * blockDim.x + threadIdx.x;
    if (p >= n_paths) return;
    float s = 0.0f;
#pragma unroll
    for (int k = 0; k < KHOPS; ++k) {
        int e = pl_edges[k * n_paths + p] - n_paths;
        s += Xl[e];
    }
    res[p] = s;
}

// ---------------------------------------------------------------------------
extern "C" void kernel_launch(void* const* d_in, const int* in_sizes, int n_in,
                              void* d_out, int out_size, void* d_ws, size_t ws_size,
                              hipStream_t stream) {
    const float* P        = (const float*)d_in[0];   // (n_paths, 3)
    const float* L        = (const float*)d_in[1];   // (n_links, 1)
    const int*   pl_edges = (const int*)d_in[3];     // (KHOPS, n_paths)

    const int n_paths = in_sizes[0] / 3;
    const int n_links = in_sizes[1];
    const int num_iterations = 3;

    // workspace: A (n_paths) | bp | rho | Xl | partial (P1*n_links) | Trep (G*n_links)
    size_t floats_avail = ws_size / sizeof(float);
    long   spare = (long)floats_avail - (long)n_paths - (long)(3 + P1) * n_links;
    int G = (int)(spare / n_links);
    if (G > MAXGRID) G = MAXGRID;
    G &= ~7;                         // multiple of 8 (XCD count)
    if (G < MINGRID) G = MINGRID;

    float* A       = (float*)d_ws;
    float* bp      = A       + n_paths;
    float* rho     = bp      + n_links;
    float* Xl      = rho     + n_links;
    float* partial = Xl      + n_links;
    float* Trep    = partial + (size_t)P1 * n_links;

    float* res       = (float*)d_out;                // (n_paths,)
    float* out_links = res + n_paths;                // (n_links, 3)

    const int bs = 256;
    const int gl = (n_links + bs - 1) / bs;
    const int gp = (n_paths + bs - 1) / bs;
    const int gi = (n_paths + bs - 1) / bs;          // n_paths > n_links

    init_kernel<<<gi, bs, 0, stream>>>(P, A, bp, n_paths, n_links);
    for (int it = 0; it < num_iterations; ++it) {
        scatter_kernel<<<G, BS, 0, stream>>>(A, pl_edges, bp, Trep,
                                             n_paths, n_links);
        merge_kernel<<<dim3(gl, P1), bs, 0, stream>>>(Trep, partial, n_links, G);
        link_update_kernel<<<gl, bs, 0, stream>>>(L, partial, bp, rho, n_links);
    }
    epilogue_kernel<<<gl, bs, 0, stream>>>(L, rho, Xl, out_links, n_links);
    gather_kernel<<<gp, bs, 0, stream>>>(pl_edges, Xl, res, n_paths);
}